// Round 1
// baseline (500.368 us; speedup 1.0000x reference)
//
#include <hip/hip_runtime.h>

// BitLinear: out[b,t,o] = scale_x[b,t] * scale_w * sum_d qx[b,t,d] * tw[o,d]
// qx = clip(round(127*x/(max|x|row + eps)), -128, 127)   (int8, exact)
// tw = clip(round(w/(mean|W| + eps)), -1, 1)             (ternary, exact)
// Integer GEMM via mfma_i32_16x16x64_i8, fp32 dequant epilogue.

#define M_ROWS 4096   // B*T
#define K_DIM  4096   // D_IN
#define N_DIM  16384  // D_OUT
#define W_ELEMS (N_DIM * K_DIM)          // 67108864
#define EPSF 1e-8f

using i32x4 = __attribute__((ext_vector_type(4))) int;

// ---------------- ws layout (bytes) ----------------
// [0, 8)        : float scales[2] = {scale_w, scale_w + eps}
// [1024, 17408) : double partials[2048]
// [32768, ...)  : float sx[4096]
// [65536, ...)  : int8 xq[4096*4096]        (16 MiB)
// [65536+16Mi)  : int8 wq[16384*4096]       (64 MiB)

// ---------- kernel 1: |W| partial sums (deterministic) ----------
__global__ void k_abs_partial(const float4* __restrict__ w4,
                              double* __restrict__ part) {
    const int tid = threadIdx.x;
    int idx = blockIdx.x * 256 + tid;
    double s = 0.0;
    #pragma unroll 4
    for (int it = 0; it < 32; ++it) {
        float4 v = w4[idx + it * (2048 * 256)];
        s += (double)fabsf(v.x) + (double)fabsf(v.y)
           + (double)fabsf(v.z) + (double)fabsf(v.w);
    }
    __shared__ double red[256];
    red[tid] = s;
    __syncthreads();
    for (int o = 128; o > 0; o >>= 1) {
        if (tid < o) red[tid] += red[tid + o];
        __syncthreads();
    }
    if (tid == 0) part[blockIdx.x] = red[0];
}

__global__ void k_abs_final(const double* __restrict__ part,
                            float* __restrict__ scales) {
    const int tid = threadIdx.x;
    double s = 0.0;
    #pragma unroll
    for (int k = 0; k < 8; ++k) s += part[tid + k * 256];
    __shared__ double red[256];
    red[tid] = s;
    __syncthreads();
    for (int o = 128; o > 0; o >>= 1) {
        if (tid < o) red[tid] += red[tid + o];
        __syncthreads();
    }
    if (tid == 0) {
        float sw = (float)(red[0] / (double)W_ELEMS);
        scales[0] = sw;
        scales[1] = sw + EPSF;
    }
}

// ---------- kernel 2: ternary weight quant ----------
__global__ void k_wquant(const float4* __restrict__ w4,
                         const float* __restrict__ scales,
                         char4* __restrict__ wq4) {
    const float seps = scales[1];
    int idx = blockIdx.x * 256 + threadIdx.x;
    const int stride = 8192 * 256;
    #pragma unroll
    for (int it = 0; it < 8; ++it) {
        int i = idx + it * stride;
        float4 v = w4[i];
        char4 q;
        q.x = (signed char)(int)fminf(fmaxf(rintf(v.x / seps), -1.0f), 1.0f);
        q.y = (signed char)(int)fminf(fmaxf(rintf(v.y / seps), -1.0f), 1.0f);
        q.z = (signed char)(int)fminf(fmaxf(rintf(v.z / seps), -1.0f), 1.0f);
        q.w = (signed char)(int)fminf(fmaxf(rintf(v.w / seps), -1.0f), 1.0f);
        wq4[i] = q;
    }
}

// ---------- kernel 3: per-token int8 activation quant ----------
__global__ void k_xquant(const float4* __restrict__ x4,
                         char4* __restrict__ xq4,
                         float* __restrict__ sx) {
    const int row = blockIdx.x, tid = threadIdx.x;
    const float4* xr = x4 + (size_t)row * (K_DIM / 4);
    float4 v[4];
    float m = 0.0f;
    #pragma unroll
    for (int j = 0; j < 4; ++j) {
        v[j] = xr[tid + j * 256];
        m = fmaxf(m, fmaxf(fmaxf(fabsf(v[j].x), fabsf(v[j].y)),
                           fmaxf(fabsf(v[j].z), fabsf(v[j].w))));
    }
    __shared__ float red[256];
    red[tid] = m;
    __syncthreads();
    for (int o = 128; o > 0; o >>= 1) {
        if (tid < o) red[tid] = fmaxf(red[tid], red[tid + o]);
        __syncthreads();
    }
    const float gamma = red[0];
    const float ge = gamma + EPSF;
    char4* out = xq4 + (size_t)row * (K_DIM / 4);
    #pragma unroll
    for (int j = 0; j < 4; ++j) {
        char4 q;
        q.x = (signed char)(int)fminf(fmaxf(rintf(127.0f * v[j].x / ge), -128.0f), 127.0f);
        q.y = (signed char)(int)fminf(fmaxf(rintf(127.0f * v[j].y / ge), -128.0f), 127.0f);
        q.z = (signed char)(int)fminf(fmaxf(rintf(127.0f * v[j].z / ge), -128.0f), 127.0f);
        q.w = (signed char)(int)fminf(fmaxf(rintf(127.0f * v[j].w / ge), -128.0f), 127.0f);
        out[tid + j * 256] = q;
    }
    if (tid == 0) sx[row] = gamma / 127.0f;
}

// ---------- kernel 4: int8 GEMM (m97 structure, 128x128 tile, BK=64) ----------
__device__ __forceinline__ void gload16(const signed char* g, const signed char* l) {
    __builtin_amdgcn_global_load_lds(
        (const __attribute__((address_space(1))) void*)g,
        (__attribute__((address_space(3))) void*)l, 16, 0, 0);
}

__global__ __launch_bounds__(256)
void k_gemm(const signed char* __restrict__ Aq,   // [4096][4096] row-major
            const signed char* __restrict__ Bq,   // [16384][4096] row-major (N x K)
            const float* __restrict__ sx,
            const float* __restrict__ scales,
            float* __restrict__ C) {
    __shared__ __align__(16) signed char sA[128 * 64];
    __shared__ __align__(16) signed char sB[128 * 64];

    const int tid  = threadIdx.x;
    const int lane = tid & 63;
    const int wid  = tid >> 6;

    // XCD-bijective swizzle (nwg=4096, divisible by 8) + group-8 tile mapping
    const int nwg = gridDim.x;
    const int cpx = nwg >> 3;
    const int bid = blockIdx.x;
    const int wg  = (bid & 7) * cpx + (bid >> 3);
    const int num_n = N_DIM / 128;          // 128
    const int per_group = 8 * num_n;        // 1024
    const int gidx   = wg / per_group;
    const int within = wg - gidx * per_group;
    const int pm = gidx * 8 + (within & 7); // [0,32)
    const int pn = within >> 3;             // [0,128)

    // Staging constants. Tile is 128 rows x 64 bytes = 8192 B; 2 issues of
    // 256thr x 16B. LDS dest is LINEAR (wave-uniform base + lane*16); the
    // XOR swizzle chunk' = chunk ^ ((row>>1)&3) is applied to the GLOBAL
    // source column so that swizzled ds_read recovers it (rule #21).
    int prow[2], pcol[2], ldsoff[2];
    #pragma unroll
    for (int i = 0; i < 2; ++i) {
        int p = i * 4096 + tid * 16;
        int r = p >> 6;
        int j = (p >> 4) & 3;
        int js = j ^ ((r >> 1) & 3);
        prow[i]  = r;
        pcol[i]  = js << 4;
        ldsoff[i] = i * 4096 + wid * 1024;  // wave-uniform base
    }
    const signed char* aSrc0 = Aq + (size_t)(pm * 128 + prow[0]) * K_DIM + pcol[0];
    const signed char* aSrc1 = Aq + (size_t)(pm * 128 + prow[1]) * K_DIM + pcol[1];
    const signed char* bSrc0 = Bq + (size_t)(pn * 128 + prow[0]) * K_DIM + pcol[0];
    const signed char* bSrc1 = Bq + (size_t)(pn * 128 + prow[1]) * K_DIM + pcol[1];

    // Fragment geometry: wave (wid>>1, wid&1) owns 64x64; 4x4 frags of 16x16.
    // mfma_i32_16x16x64_i8 A-frag: lane holds row=(lane&15), k=(lane>>4)*16+j
    // (16 contiguous bytes -> one swizzled ds_read_b128).
    const int wm  = (wid >> 1) * 64;
    const int wn  = (wid & 1) * 64;
    const int l15 = lane & 15;
    const int chunk = ((lane >> 4) ^ ((l15 >> 1) & 3)) << 4;  // swizzled 16B slot

    i32x4 acc[4][4];
    #pragma unroll
    for (int a = 0; a < 4; ++a)
        #pragma unroll
        for (int b = 0; b < 4; ++b)
            acc[a][b] = (i32x4){0, 0, 0, 0};

    for (int kt = 0; kt < K_DIM / 64; ++kt) {
        const int ko = kt * 64;
        gload16(aSrc0 + ko, sA + ldsoff[0]);
        gload16(aSrc1 + ko, sA + ldsoff[1]);
        gload16(bSrc0 + ko, sB + ldsoff[0]);
        gload16(bSrc1 + ko, sB + ldsoff[1]);
        __syncthreads();   // compiler emits vmcnt(0) drain before barrier

        i32x4 af[4], bf[4];
        #pragma unroll
        for (int f = 0; f < 4; ++f) {
            af[f] = *(const i32x4*)(sA + (wm + f * 16 + l15) * 64 + chunk);
            bf[f] = *(const i32x4*)(sB + (wn + f * 16 + l15) * 64 + chunk);
        }
        #pragma unroll
        for (int fm = 0; fm < 4; ++fm)
            #pragma unroll
            for (int fn = 0; fn < 4; ++fn)
                acc[fm][fn] = __builtin_amdgcn_mfma_i32_16x16x64_i8(
                    af[fm], bf[fn], acc[fm][fn], 0, 0, 0);
        __syncthreads();   // protect LDS before next stage
    }

    // Epilogue: C/D frag (16x16): col=lane&15, row=(lane>>4)*4+reg
    const float sw = scales[0];
    const int gn0 = pn * 128 + wn + l15;
    const int gm_base = pm * 128 + wm + (lane >> 4) * 4;
    #pragma unroll
    for (int fm = 0; fm < 4; ++fm) {
        #pragma unroll
        for (int r = 0; r < 4; ++r) {
            const int gm = gm_base + fm * 16 + r;
            const float s = sx[gm] * sw;
            float* crow = C + (size_t)gm * N_DIM + gn0;
            #pragma unroll
            for (int fn = 0; fn < 4; ++fn)
                crow[fn * 16] = (float)acc[fm][fn][r] * s;
        }
    }
}

extern "C" void kernel_launch(void* const* d_in, const int* in_sizes, int n_in,
                              void* d_out, int out_size, void* d_ws, size_t ws_size,
                              hipStream_t stream) {
    const float* x = (const float*)d_in[0];   // (2,2048,4096) f32
    const float* w = (const float*)d_in[1];   // (16384,4096) f32
    float* out = (float*)d_out;               // (2,2048,16384) f32
    char* ws = (char*)d_ws;

    float*  scales = (float*)(ws);                     // 2 floats
    double* part   = (double*)(ws + 1024);             // 2048 doubles
    float*  sx     = (float*)(ws + 32 * 1024);         // 4096 floats
    signed char* xq = (signed char*)(ws + 64 * 1024);  // 16 MiB
    signed char* wq = xq + (size_t)M_ROWS * K_DIM;     // 64 MiB

    k_abs_partial<<<2048, 256, 0, stream>>>((const float4*)w, part);
    k_abs_final<<<1, 256, 0, stream>>>(part, scales);
    k_wquant<<<8192, 256, 0, stream>>>((const float4*)w, scales, (char4*)wq);
    k_xquant<<<M_ROWS, 256, 0, stream>>>((const float4*)x, (char4*)xq, sx);
    k_gemm<<<(M_ROWS / 128) * (N_DIM / 128), 256, 0, stream>>>(xq, wq, sx, scales, out);
}

// Round 2
// 402.911 us; speedup vs baseline: 1.2419x; 1.2419x over previous
//
#include <hip/hip_runtime.h>

// BitLinear: out[b,t,o] = scale_x[b,t] * scale_w * sum_d qx[b,t,d] * tw[o,d]
// qx = clip(round(127*x/(max|x|row + eps)), -128, 127)   (int8, exact)
// tw = clip(round(w/(mean|W| + eps)), -1, 1)             (ternary, exact)
// Integer GEMM via mfma_i32_16x16x64_i8, fp32 dequant epilogue.
// R2: GEMM moved to 256x256 8-phase schedule (T2 swizzle + T3/T4 counted
// vmcnt + T5 setprio), i8 port of the m201 template.

#define M_ROWS 4096   // B*T
#define K_DIM  4096   // D_IN
#define N_DIM  16384  // D_OUT
#define W_ELEMS (N_DIM * K_DIM)          // 67108864
#define EPSF 1e-8f

using i32x4 = __attribute__((ext_vector_type(4))) int;

// ---------------- ws layout (bytes) ----------------
// [0, 8)        : float scales[2] = {scale_w, scale_w + eps}
// [1024, 17408) : double partials[2048]
// [32768, ...)  : float sx[4096]
// [65536, ...)  : int8 xq[4096*4096]        (16 MiB)
// [65536+16Mi)  : int8 wq[16384*4096]       (64 MiB)

// ---------- kernel 1: |W| partial sums (deterministic) ----------
__global__ void k_abs_partial(const float4* __restrict__ w4,
                              double* __restrict__ part) {
    const int tid = threadIdx.x;
    int idx = blockIdx.x * 256 + tid;
    double s = 0.0;
    #pragma unroll 4
    for (int it = 0; it < 32; ++it) {
        float4 v = w4[idx + it * (2048 * 256)];
        s += (double)fabsf(v.x) + (double)fabsf(v.y)
           + (double)fabsf(v.z) + (double)fabsf(v.w);
    }
    __shared__ double red[256];
    red[tid] = s;
    __syncthreads();
    for (int o = 128; o > 0; o >>= 1) {
        if (tid < o) red[tid] += red[tid + o];
        __syncthreads();
    }
    if (tid == 0) part[blockIdx.x] = red[0];
}

__global__ void k_abs_final(const double* __restrict__ part,
                            float* __restrict__ scales) {
    const int tid = threadIdx.x;
    double s = 0.0;
    #pragma unroll
    for (int k = 0; k < 8; ++k) s += part[tid + k * 256];
    __shared__ double red[256];
    red[tid] = s;
    __syncthreads();
    for (int o = 128; o > 0; o >>= 1) {
        if (tid < o) red[tid] += red[tid + o];
        __syncthreads();
    }
    if (tid == 0) {
        float sw = (float)(red[0] / (double)W_ELEMS);
        scales[0] = sw;
        scales[1] = sw + EPSF;
    }
}

// ---------- kernel 2: ternary weight quant ----------
__global__ void k_wquant(const float4* __restrict__ w4,
                         const float* __restrict__ scales,
                         char4* __restrict__ wq4) {
    const float seps = scales[1];
    int idx = blockIdx.x * 256 + threadIdx.x;
    const int stride = 8192 * 256;
    #pragma unroll
    for (int it = 0; it < 8; ++it) {
        int i = idx + it * stride;
        float4 v = w4[i];
        char4 q;
        q.x = (signed char)(int)fminf(fmaxf(rintf(v.x / seps), -1.0f), 1.0f);
        q.y = (signed char)(int)fminf(fmaxf(rintf(v.y / seps), -1.0f), 1.0f);
        q.z = (signed char)(int)fminf(fmaxf(rintf(v.z / seps), -1.0f), 1.0f);
        q.w = (signed char)(int)fminf(fmaxf(rintf(v.w / seps), -1.0f), 1.0f);
        wq4[i] = q;
    }
}

// ---------- kernel 3: per-token int8 activation quant ----------
__global__ void k_xquant(const float4* __restrict__ x4,
                         char4* __restrict__ xq4,
                         float* __restrict__ sx) {
    const int row = blockIdx.x, tid = threadIdx.x;
    const float4* xr = x4 + (size_t)row * (K_DIM / 4);
    float4 v[4];
    float m = 0.0f;
    #pragma unroll
    for (int j = 0; j < 4; ++j) {
        v[j] = xr[tid + j * 256];
        m = fmaxf(m, fmaxf(fmaxf(fabsf(v[j].x), fabsf(v[j].y)),
                           fmaxf(fabsf(v[j].z), fabsf(v[j].w))));
    }
    __shared__ float red[256];
    red[tid] = m;
    __syncthreads();
    for (int o = 128; o > 0; o >>= 1) {
        if (tid < o) red[tid] = fmaxf(red[tid], red[tid + o]);
        __syncthreads();
    }
    const float gamma = red[0];
    const float ge = gamma + EPSF;
    char4* out = xq4 + (size_t)row * (K_DIM / 4);
    #pragma unroll
    for (int j = 0; j < 4; ++j) {
        char4 q;
        q.x = (signed char)(int)fminf(fmaxf(rintf(127.0f * v[j].x / ge), -128.0f), 127.0f);
        q.y = (signed char)(int)fminf(fmaxf(rintf(127.0f * v[j].y / ge), -128.0f), 127.0f);
        q.z = (signed char)(int)fminf(fmaxf(rintf(127.0f * v[j].z / ge), -128.0f), 127.0f);
        q.w = (signed char)(int)fminf(fmaxf(rintf(127.0f * v[j].w / ge), -128.0f), 127.0f);
        out[tid + j * 256] = q;
    }
    if (tid == 0) sx[row] = gamma / 127.0f;
}

// ---------- kernel 4: int8 GEMM, 256x256 tile, 8-phase schedule ----------
__device__ __forceinline__ void gload16(const signed char* g, signed char* l) {
    __builtin_amdgcn_global_load_lds(
        (const __attribute__((address_space(1))) void*)g,
        (__attribute__((address_space(3))) void*)l, 16, 0, 0);
}

#define BAR()   __builtin_amdgcn_s_barrier()
#define LGKM0() asm volatile("s_waitcnt lgkmcnt(0)" ::: "memory")
#define VM6()   asm volatile("s_waitcnt vmcnt(6)" ::: "memory")
#define PRIO1() __builtin_amdgcn_s_setprio(1)
#define PRIO0() __builtin_amdgcn_s_setprio(0)

// Geometry: BM=BN=256, BK=128 i8 (=128 B/row, 2 MFMA K-slices of 64).
// 8 waves (2M x 4N), per-wave 128x64 out = 8x4 frags of 16x16 (128 acc VGPRs).
// LDS: 2 dbuf x (A 32 KiB + B 32 KiB) = 128 KiB, canonical [256 rows][128 B]
// with chunk-XOR swizzle: LDS[row][c] holds G[row][c ^ (row&7)] (16-B chunks).
// global_load_lds writes linearly (lane*16), so the source is pre-swizzled
// (rule #21); ds_read_b128 applies the same XOR -> <=2-way bank alias (free).
// Stage schedule: each phase stages the region freed by the previous phase's
// reads, 1-phase lag; vmcnt(6) gate only at phases 4/8 (7 half-tiles of 2
// loads in flight, drain to 3).
__global__ __launch_bounds__(512, 2)
void k_gemm8(const signed char* __restrict__ Aq,   // [4096][4096]  (M x K)
             const signed char* __restrict__ Bq,   // [16384][4096] (N x K)
             const float* __restrict__ sx,
             const float* __restrict__ scales,
             float* __restrict__ C) {
    __shared__ __align__(16) signed char lds[131072];

    const int tid  = threadIdx.x;
    const int lane = tid & 63;
    const int wid  = tid >> 6;
    const int l15  = lane & 15;
    const int qg   = lane >> 4;
    const int swz  = l15 & 7;

    // XCD-bijective swizzle (nwg=1024 % 8 == 0) + supergroup-of-8-pm mapping
    const int bid = blockIdx.x;
    const int wg  = (bid & 7) * 128 + (bid >> 3);
    const int gidx   = wg >> 9;           // 64 n-tiles * 8 m-rows = 512/group
    const int within = wg & 511;
    const int pm = gidx * 8 + (within & 7);   // [0,16)
    const int pn = within >> 3;               // [0,64)

    const int wm = (wid >> 2) * 128;
    const int wn = (wid & 3) * 64;

    // staging: per-lane pre-swizzled source offset. Each gload_lds writes
    // 1 KiB = 8 rows x 128 B starting at a wave-uniform row base r0; lane l
    // covers row r0+(l>>3), chunk l&7, so source chunk = (l&7)^(l>>3).
    const int l3 = lane >> 3, l7 = lane & 7;
    const int lane_off = l3 * K_DIM + ((l7 ^ l3) << 4);
    const signed char* Asrc = Aq + (size_t)(pm * 256) * K_DIM + lane_off;
    const signed char* Bsrc = Bq + (size_t)(pn * 256) * K_DIM + lane_off;
    const int ar0 = wid * 8;                          // + mh*64 (+128 for 2nd instr)
    const int br0 = (wid >> 2) * 64 + (wid & 3) * 8;  // + nh*32 (+128 for 2nd instr)

    auto stageA = [&](int buf, int mh, int kt) {
        const int r0 = mh * 64 + ar0;
        const signed char* s = Asrc + (size_t)r0 * K_DIM + kt * 128;
        signed char* d = lds + buf * 65536 + r0 * 128;
        gload16(s, d);
        gload16(s + (size_t)128 * K_DIM, d + 128 * 128);
    };
    auto stageB = [&](int buf, int nh, int kt) {
        const int r0 = nh * 32 + br0;
        const signed char* s = Bsrc + (size_t)r0 * K_DIM + kt * 128;
        signed char* d = lds + buf * 65536 + 32768 + r0 * 128;
        gload16(s, d);
        gload16(s + (size_t)128 * K_DIM, d + 128 * 128);
    };

    i32x4 acc[8][4];
    #pragma unroll
    for (int a = 0; a < 8; ++a)
        #pragma unroll
        for (int b = 0; b < 4; ++b)
            acc[a][b] = (i32x4){0, 0, 0, 0};

    i32x4 af[8], bf[4];
    auto ldA = [&](int buf, int mh) {
        const signed char* base = lds + buf * 65536;
        #pragma unroll
        for (int fm = 0; fm < 4; ++fm) {
            const int ro = (wm + mh * 64 + fm * 16 + l15) * 128;
            #pragma unroll
            for (int ks = 0; ks < 2; ++ks)
                af[fm * 2 + ks] = *(const i32x4*)(base + ro + (((ks * 4 + qg) ^ swz) << 4));
        }
    };
    auto ldB = [&](int buf, int nh) {
        const signed char* base = lds + buf * 65536 + 32768;
        #pragma unroll
        for (int fn = 0; fn < 2; ++fn) {
            const int ro = (wn + nh * 32 + fn * 16 + l15) * 128;
            #pragma unroll
            for (int ks = 0; ks < 2; ++ks)
                bf[fn * 2 + ks] = *(const i32x4*)(base + ro + (((ks * 4 + qg) ^ swz) << 4));
        }
    };
    auto mma = [&](int mh, int nh) {
        #pragma unroll
        for (int ks = 0; ks < 2; ++ks)
            #pragma unroll
            for (int fm = 0; fm < 4; ++fm)
                #pragma unroll
                for (int fn = 0; fn < 2; ++fn)
                    acc[mh * 4 + fm][nh * 2 + fn] = __builtin_amdgcn_mfma_i32_16x16x64_i8(
                        af[fm * 2 + ks], bf[fn * 2 + ks], acc[mh * 4 + fm][nh * 2 + fn], 0, 0, 0);
    };

    // ---- prologue: K-tile 0 -> buf0 (4 half-tiles), K-tile 1 -> buf1 (3) ----
    stageA(0, 0, 0); stageB(0, 1, 0); stageA(0, 1, 0); stageB(0, 0, 0);
    stageA(1, 0, 1); stageB(1, 1, 1); stageA(1, 1, 1);
    VM6();   // drain buf0's 8 loads, leave buf1's 6 in flight
    BAR();

    // ---- main loop: 16 iters x 2 K-tiles ----
    for (int t = 0; t < 16; ++t) {
        const int k1 = 2 * t + 1;
        const int k2 = (2 * t + 2) & 31;   // wrap on last iter: harmless garbage stage
        const int k3 = (2 * t + 3) & 31;

        // phase 1: quad (0,0) on buf0 | stage B.nh0(k1) -> buf1
        ldA(0, 0); ldB(0, 0); stageB(1, 0, k1);
        BAR(); LGKM0(); PRIO1(); mma(0, 0); PRIO0(); BAR();
        // phase 2: quad (0,1) | stage A.mh0(k2) -> buf0 (freed by p1)
        ldB(0, 1); stageA(0, 0, k2);
        BAR(); LGKM0(); PRIO1(); mma(0, 1); PRIO0(); BAR();
        // phase 3: quad (1,1) | stage B.nh1(k2) (freed by p2)
        ldA(0, 1); stageB(0, 1, k2);
        BAR(); LGKM0(); PRIO1(); mma(1, 1); PRIO0(); BAR();
        // phase 4: quad (1,0) | stage A.mh1(k2) (freed by p3) | GATE
        ldB(0, 0); stageA(0, 1, k2);
        BAR(); LGKM0(); PRIO1(); mma(1, 0); PRIO0();
        VM6();   // buf1 K-tile k1 fully landed; p2/p3/p4 loads stay in flight
        BAR();
        // phase 5: quad (0,0) on buf1 | stage B.nh0(k2) -> buf0 (freed by p4)
        ldA(1, 0); ldB(1, 0); stageB(0, 0, k2);
        BAR(); LGKM0(); PRIO1(); mma(0, 0); PRIO0(); BAR();
        // phase 6: quad (0,1) | stage A.mh0(k3) -> buf1 (freed by p5)
        ldB(1, 1); stageA(1, 0, k3);
        BAR(); LGKM0(); PRIO1(); mma(0, 1); PRIO0(); BAR();
        // phase 7: quad (1,1) | stage B.nh1(k3) (freed by p6)
        ldA(1, 1); stageB(1, 1, k3);
        BAR(); LGKM0(); PRIO1(); mma(1, 1); PRIO0(); BAR();
        // phase 8: quad (1,0) | stage A.mh1(k3) (freed by p7) | GATE
        ldB(1, 0); stageA(1, 1, k3);
        BAR(); LGKM0(); PRIO1(); mma(1, 0); PRIO0();
        VM6();   // buf0 K-tile k2 fully landed
        BAR();
    }
    asm volatile("s_waitcnt vmcnt(0)" ::: "memory");  // drain tail garbage stages

    // ---- epilogue: C/D frag: col=lane&15, row=(lane>>4)*4+reg ----
    const float sw = scales[0];
    const int gn0 = pn * 256 + wn + l15;
    const int rb  = (lane >> 4) * 4;
    #pragma unroll
    for (int mi = 0; mi < 8; ++mi) {
        const int rowoff = (mi >> 2) * 64 + (mi & 3) * 16;
        #pragma unroll
        for (int r = 0; r < 4; ++r) {
            const int gm = pm * 256 + wm + rowoff + rb + r;
            const float s = sx[gm] * sw;
            float* crow = C + (size_t)gm * N_DIM + gn0;
            #pragma unroll
            for (int ni = 0; ni < 4; ++ni)
                crow[(ni >> 1) * 32 + (ni & 1) * 16] = (float)acc[mi][ni][r] * s;
        }
    }
}

extern "C" void kernel_launch(void* const* d_in, const int* in_sizes, int n_in,
                              void* d_out, int out_size, void* d_ws, size_t ws_size,
                              hipStream_t stream) {
    const float* x = (const float*)d_in[0];   // (2,2048,4096) f32
    const float* w = (const float*)d_in[1];   // (16384,4096) f32
    float* out = (float*)d_out;               // (2,2048,16384) f32
    char* ws = (char*)d_ws;

    float*  scales = (float*)(ws);                     // 2 floats
    double* part   = (double*)(ws + 1024);             // 2048 doubles
    float*  sx     = (float*)(ws + 32 * 1024);         // 4096 floats
    signed char* xq = (signed char*)(ws + 64 * 1024);  // 16 MiB
    signed char* wq = xq + (size_t)M_ROWS * K_DIM;     // 64 MiB

    k_abs_partial<<<2048, 256, 0, stream>>>((const float4*)w, part);
    k_abs_final<<<1, 256, 0, stream>>>(part, scales);
    k_wquant<<<8192, 256, 0, stream>>>((const float4*)w, scales, (char4*)wq);
    k_xquant<<<M_ROWS, 256, 0, stream>>>((const float4*)x, (char4*)xq, sx);
    k_gemm8<<<(M_ROWS / 256) * (N_DIM / 256), 512, 0, stream>>>(xq, wq, sx, scales, out);
}